// Round 4
// baseline (850.693 us; speedup 1.0000x reference)
//
#include <hip/hip_runtime.h>

typedef unsigned short ushort_t;
typedef unsigned int uint32;
typedef __bf16 bf16x8 __attribute__((ext_vector_type(8)));
typedef float f32x4 __attribute__((ext_vector_type(4)));

#define MFMA16(a, b, c) __builtin_amdgcn_mfma_f32_16x16x32_bf16((a), (b), (c), 0, 0, 0)

__device__ __forceinline__ ushort_t f2bf(float f) {
  union { float f; uint32 u; } c; c.f = f;
  uint32 u = c.u;
  u += 0x7fffu + ((u >> 16) & 1u);   // round-to-nearest-even
  return (ushort_t)(u >> 16);
}

// async global->LDS, 16B per lane. LDS dest must be wave-uniform base + lane*16.
__device__ __forceinline__ void gload_lds16(const void* g, void* l) {
  __builtin_amdgcn_global_load_lds(
      (const __attribute__((address_space(1))) void*)g,
      (__attribute__((address_space(3))) void*)l, 16, 0, 0);
}

// ---------------------------------------------------------------------------
// C[M,N] = A[M,K] @ W[N,K]^T + bias[N]. A,W fp32 (converted to bf16 during
// staging); bias fp32; C bf16; fp32 accum. 128x128 tile, BK=32, 4 waves (2x2),
// each wave 64x64 = 4x4 frags. grid = (N/128, M/128), block = 256.
// ---------------------------------------------------------------------------
__global__ __launch_bounds__(256)
void gemm_f32_bt_kernel(const float* __restrict__ A, const float* __restrict__ W,
                        const float* __restrict__ bias, ushort_t* __restrict__ C,
                        int N, int Kd)
{
  __shared__ __attribute__((aligned(16))) ushort_t As[128 * 32];
  __shared__ __attribute__((aligned(16))) ushort_t Bs[128 * 32];
  const int tid = threadIdx.x;
  const int lane = tid & 63;
  const int wv = tid >> 6;
  const int wr = wv >> 1, wc = wv & 1;
  const int bn = blockIdx.x, bm = blockIdx.y;
  const int l15 = lane & 15, lg = lane >> 4;

  f32x4 acc[4][4] = {};
  const int nk = Kd >> 5;
  const size_t rowA0 = (size_t)bm * 128;
  const size_t rowB0 = (size_t)bn * 128;

  for (int kt = 0; kt < nk; ++kt) {
    // ---- load fp32, convert to bf16 in regs (8 elems x 2 halves per tensor) ----
    union { uint4 u; ushort_t s[8]; } astg[2], bstg[2];
#pragma unroll
    for (int i = 0; i < 2; ++i) {
      const int idx = (i * 256 + tid) * 8;   // element index in 128x32 tile
      const int row = idx >> 5;
      const int c0 = idx & 31;
      const float* ag = A + (rowA0 + row) * Kd + kt * 32 + c0;
      const float* wg = W + (rowB0 + row) * Kd + kt * 32 + c0;
      float4 ax = *(const float4*)ag, ay = *(const float4*)(ag + 4);
      float4 wx = *(const float4*)wg, wy = *(const float4*)(wg + 4);
      astg[i].s[0] = f2bf(ax.x); astg[i].s[1] = f2bf(ax.y);
      astg[i].s[2] = f2bf(ax.z); astg[i].s[3] = f2bf(ax.w);
      astg[i].s[4] = f2bf(ay.x); astg[i].s[5] = f2bf(ay.y);
      astg[i].s[6] = f2bf(ay.z); astg[i].s[7] = f2bf(ay.w);
      bstg[i].s[0] = f2bf(wx.x); bstg[i].s[1] = f2bf(wx.y);
      bstg[i].s[2] = f2bf(wx.z); bstg[i].s[3] = f2bf(wx.w);
      bstg[i].s[4] = f2bf(wy.x); bstg[i].s[5] = f2bf(wy.y);
      bstg[i].s[6] = f2bf(wy.z); bstg[i].s[7] = f2bf(wy.w);
    }
    __syncthreads();   // previous iteration's LDS reads complete
#pragma unroll
    for (int i = 0; i < 2; ++i) {
      const int idx = (i * 256 + tid) * 8;
      *(uint4*)(As + idx) = astg[i].u;
      *(uint4*)(Bs + idx) = bstg[i].u;
    }
    __syncthreads();   // tile staged

    bf16x8 af[4], bfr[4];
#pragma unroll
    for (int mi = 0; mi < 4; ++mi)
      af[mi] = *(const bf16x8*)&As[(wr * 64 + mi * 16 + l15) * 32 + lg * 8];
#pragma unroll
    for (int nj = 0; nj < 4; ++nj)
      bfr[nj] = *(const bf16x8*)&Bs[(wc * 64 + nj * 16 + l15) * 32 + lg * 8];
#pragma unroll
    for (int mi = 0; mi < 4; ++mi)
#pragma unroll
      for (int nj = 0; nj < 4; ++nj)
        acc[mi][nj] = MFMA16(af[mi], bfr[nj], acc[mi][nj]);
  }

  // epilogue: C/D layout row=(lg*4+r), col=l15 within each 16x16 frag
#pragma unroll
  for (int nj = 0; nj < 4; ++nj) {
    int col = bn * 128 + wc * 64 + nj * 16 + l15;
    float bv = bias[col];
#pragma unroll
    for (int mi = 0; mi < 4; ++mi) {
      int row0 = bm * 128 + wr * 64 + mi * 16 + lg * 4;
#pragma unroll
      for (int r = 0; r < 4; ++r)
        C[(size_t)(row0 + r) * N + col] = f2bf(acc[mi][nj][r] + bv);
    }
  }
}

// ---------------------------------------------------------------------------
// Flash attention, causal, GQA — UNCHANGED (bisect control).
// Q/ctx: [B*S, 3072] (col = h*128+d), K/V: [B*S, 1024] (col = kvh*128+d).
// grid = (S/64, B*NH), block = 256. Wave w owns q rows [q0+16w, q0+16w+16).
// ---------------------------------------------------------------------------
#define NHEADS 24
#define GRP 3
#define SEQ 2048
#define SCALE 0.08838834764831845f
#define PSTR 88   // P-buffer stride in elements: 176B = 16B-aligned, 2-way bank (free)

__global__ __launch_bounds__(256)
void attn_kernel(const ushort_t* __restrict__ Q, const ushort_t* __restrict__ K,
                 const ushort_t* __restrict__ V, ushort_t* __restrict__ O)
{
  __shared__ __attribute__((aligned(16))) ushort_t Kl[64 * 128];     // swizzled [kv][d]
  __shared__ __attribute__((aligned(16))) ushort_t Vt[128 * 64];     // swizzled [d][kv]
  __shared__ __attribute__((aligned(16))) ushort_t Pl[4][16 * PSTR]; // per-wave P

  const int tid = threadIdx.x;
  const int lane = tid & 63;
  const int wv = tid >> 6;
  const int l15 = lane & 15, lg = lane >> 4;
  const int qb = blockIdx.x;
  const int bh = blockIdx.y;
  const int b = bh / NHEADS, h = bh % NHEADS;
  const int kvh = h / GRP;
  const int q0 = qb * 64;

  // Q fragments in registers: rows q0+wv*16+l15, d chunks of 32
  bf16x8 qf[4];
  {
    const ushort_t* qg = Q + (size_t)(b * SEQ + q0 + wv * 16 + l15) * 3072 + h * 128 + lg * 8;
#pragma unroll
    for (int c = 0; c < 4; ++c) qf[c] = *(const bf16x8*)(qg + c * 32);
  }

  float m_st[4], l_st[4];
#pragma unroll
  for (int r = 0; r < 4; ++r) { m_st[r] = -1e30f; l_st[r] = 0.f; }
  f32x4 accO[8] = {};

  const size_t kbase = (size_t)b * SEQ * 1024 + (size_t)kvh * 128;

  for (int t = 0; t <= qb; ++t) {
    const int kv0 = t * 64;
    // ---- stage K tile, swizzle via pre-swizzled global source ----
#pragma unroll
    for (int i = 0; i < 4; ++i) {
      int o = (i * 256 + tid) * 16;   // LDS byte offset, 256B per kv row
      int row = o >> 8;
      int within = o & 255;
      int src = within ^ ((row & 7) << 4);
      gload_lds16(K + kbase + (size_t)(kv0 + row) * 1024 + (src >> 1), (char*)Kl + o);
    }
    // ---- stage V transposed: Vt[d][kv], swizzled ----
    {
      int kvr = tid & 63;
      int d0 = (tid >> 6) * 32;
      const ushort_t* vg = V + kbase + (size_t)(kv0 + kvr) * 1024 + d0;
#pragma unroll
      for (int cc = 0; cc < 4; ++cc) {
        union { uint4 u; ushort_t s[8]; } vvv;
        vvv.u = *(const uint4*)(vg + cc * 8);
#pragma unroll
        for (int e = 0; e < 8; ++e) {
          int d = d0 + cc * 8 + e;
          int off = (d * 128 + kvr * 2) ^ ((d & 7) << 4);
          *(ushort_t*)((char*)Vt + off) = vvv.s[e];
        }
      }
    }
    __syncthreads();

    // ---- scores: S[16q][64kv] per wave, 4 col-frags x 4 d-chunks ----
    f32x4 s[4];
#pragma unroll
    for (int n = 0; n < 4; ++n) {
      f32x4 z = {0.f, 0.f, 0.f, 0.f};
      s[n] = z;
#pragma unroll
      for (int c = 0; c < 4; ++c) {
        int row = n * 16 + l15;
        int boff = (row * 256 + c * 64 + lg * 16) ^ ((row & 7) << 4);
        bf16x8 kf = *(const bf16x8*)((const char*)Kl + boff);
        s[n] = MFMA16(qf[c], kf, s[n]);
      }
    }

    // scale + causal mask (only diagonal tile has masked entries)
    if (t == qb) {
#pragma unroll
      for (int n = 0; n < 4; ++n)
#pragma unroll
        for (int r = 0; r < 4; ++r) {
          int kvc = n * 16 + l15;
          int qr = wv * 16 + lg * 4 + r;
          s[n][r] = (kvc > qr) ? -1e9f : s[n][r] * SCALE;
        }
    } else {
#pragma unroll
      for (int n = 0; n < 4; ++n)
#pragma unroll
        for (int r = 0; r < 4; ++r) s[n][r] *= SCALE;
    }

    // online softmax: row (q = lg*4+r) lives on the 16 consecutive lanes of group lg
    float mnew[4], alpha[4], rsum[4];
#pragma unroll
    for (int r = 0; r < 4; ++r) {
      float mx = fmaxf(fmaxf(s[0][r], s[1][r]), fmaxf(s[2][r], s[3][r]));
#pragma unroll
      for (int off = 1; off < 16; off <<= 1)
        mx = fmaxf(mx, __shfl_xor(mx, off, 64));
      mnew[r] = fmaxf(m_st[r], mx);
      alpha[r] = __expf(m_st[r] - mnew[r]);
      m_st[r] = mnew[r];
      rsum[r] = 0.f;
    }

    ushort_t* Pw = &Pl[wv][0];
#pragma unroll
    for (int n = 0; n < 4; ++n)
#pragma unroll
      for (int r = 0; r < 4; ++r) {
        float p = __expf(s[n][r] - mnew[r]);
        rsum[r] += p;
        Pw[(lg * 4 + r) * PSTR + n * 16 + l15] = f2bf(p);
      }
#pragma unroll
    for (int r = 0; r < 4; ++r) {
      float sm = rsum[r];
#pragma unroll
      for (int off = 1; off < 16; off <<= 1)
        sm += __shfl_xor(sm, off, 64);
      l_st[r] = l_st[r] * alpha[r] + sm;
    }

    // rescale running O
#pragma unroll
    for (int j = 0; j < 8; ++j)
#pragma unroll
      for (int r = 0; r < 4; ++r) accO[j][r] *= alpha[r];

    // ---- PV: O[16q][128d] += P[16q][64kv] @ V[64kv][128d] ----
#pragma unroll
    for (int c = 0; c < 2; ++c) {
      bf16x8 pa = *(const bf16x8*)&Pw[l15 * PSTR + c * 32 + lg * 8];
#pragma unroll
      for (int j = 0; j < 8; ++j) {
        int d = j * 16 + l15;
        int off = (d * 128 + c * 64 + lg * 16) ^ ((d & 7) << 4);
        bf16x8 vf = *(const bf16x8*)((const char*)Vt + off);
        accO[j] = MFMA16(pa, vf, accO[j]);
      }
    }
    __syncthreads();
  }

  // epilogue: normalize and store ctx
  float inv[4];
#pragma unroll
  for (int r = 0; r < 4; ++r) inv[r] = 1.0f / l_st[r];
  ushort_t* og = O + (size_t)(b * SEQ + q0 + wv * 16 + lg * 4) * 3072 + h * 128 + l15;
#pragma unroll
  for (int j = 0; j < 8; ++j)
#pragma unroll
    for (int r = 0; r < 4; ++r)
      og[(size_t)r * 3072 + j * 16] = f2bf(accO[j][r] * inv[r]);
}

// ---------------------------------------------------------------------------
// Final GEMM: A bf16 (ctx ws), W fp32, OUTPUT fp32 (d_out is float* — the
// reference returns float32; rounds 2/3 wrongly wrote bf16 here).
// ---------------------------------------------------------------------------
__global__ __launch_bounds__(256)
void gemm_out_kernel(const ushort_t* __restrict__ A, const float* __restrict__ W,
                     const float* __restrict__ bias, float* __restrict__ C,
                     int N, int Kd)
{
  __shared__ __attribute__((aligned(16))) ushort_t As[128 * 32];
  __shared__ __attribute__((aligned(16))) ushort_t Bs[128 * 32];
  const int tid = threadIdx.x;
  const int lane = tid & 63;
  const int wv = tid >> 6;
  const int wr = wv >> 1, wc = wv & 1;
  const int bn = blockIdx.x, bm = blockIdx.y;
  const int l15 = lane & 15, lg = lane >> 4;

  f32x4 acc[4][4] = {};
  const int nk = Kd >> 5;
  const size_t rowA0 = (size_t)bm * 128;
  const size_t rowB0 = (size_t)bn * 128;

  for (int kt = 0; kt < nk; ++kt) {
    union { uint4 u; ushort_t s[8]; } bstg[2];
#pragma unroll
    for (int i = 0; i < 2; ++i) {
      const int idx = (i * 256 + tid) * 8;
      const int row = idx >> 5;
      const int c0 = idx & 31;
      const float* wg = W + (rowB0 + row) * Kd + kt * 32 + c0;
      float4 wx = *(const float4*)wg, wy = *(const float4*)(wg + 4);
      bstg[i].s[0] = f2bf(wx.x); bstg[i].s[1] = f2bf(wx.y);
      bstg[i].s[2] = f2bf(wx.z); bstg[i].s[3] = f2bf(wx.w);
      bstg[i].s[4] = f2bf(wy.x); bstg[i].s[5] = f2bf(wy.y);
      bstg[i].s[6] = f2bf(wy.z); bstg[i].s[7] = f2bf(wy.w);
    }
    __syncthreads();
#pragma unroll
    for (int i = 0; i < 2; ++i) {
      const int idx = (i * 256 + tid) * 8;
      *(uint4*)(Bs + idx) = bstg[i].u;
      int o = idx * 2;  // byte offset for A staging (bf16, async)
      int row = o >> 6;
      int cb = o & 63;
      gload_lds16(A + (rowA0 + row) * Kd + kt * 32 + (cb >> 1), (char*)As + o);
    }
    __syncthreads();

    bf16x8 af[4], bfr[4];
#pragma unroll
    for (int mi = 0; mi < 4; ++mi)
      af[mi] = *(const bf16x8*)&As[(wr * 64 + mi * 16 + l15) * 32 + lg * 8];
#pragma unroll
    for (int nj = 0; nj < 4; ++nj)
      bfr[nj] = *(const bf16x8*)&Bs[(wc * 64 + nj * 16 + l15) * 32 + lg * 8];
#pragma unroll
    for (int mi = 0; mi < 4; ++mi)
#pragma unroll
      for (int nj = 0; nj < 4; ++nj)
        acc[mi][nj] = MFMA16(af[mi], bfr[nj], acc[mi][nj]);
  }

#pragma unroll
  for (int nj = 0; nj < 4; ++nj) {
    int col = bn * 128 + wc * 64 + nj * 16 + l15;
    float bv = bias[col];
#pragma unroll
    for (int mi = 0; mi < 4; ++mi) {
      int row0 = bm * 128 + wr * 64 + mi * 16 + lg * 4;
#pragma unroll
      for (int r = 0; r < 4; ++r)
        C[(size_t)(row0 + r) * N + col] = acc[mi][nj][r] + bv;   // fp32 store
    }
  }
}

// ---------------------------------------------------------------------------
extern "C" void kernel_launch(void* const* d_in, const int* in_sizes, int n_in,
                              void* d_out, int out_size, void* d_ws, size_t ws_size,
                              hipStream_t stream) {
  // Inputs fp32 (in_npz 139.9MB ≈ 151MB raw * zlib). Output fp32 (reference
  // returns float32; harness rule: d_out dtype = reference output dtype).
  const float* hs = (const float*)d_in[0];
  // d_in[1] = attention_mask (causal by construction; applied analytically)
  const float* Wq = (const float*)d_in[2];
  const float* bq = (const float*)d_in[3];
  const float* Wk = (const float*)d_in[4];
  const float* bk = (const float*)d_in[5];
  const float* Wv = (const float*)d_in[6];
  const float* bv = (const float*)d_in[7];
  const float* Wd = (const float*)d_in[8];
  const float* bd = (const float*)d_in[9];
  float* out = (float*)d_out;

  // workspace: 67.1 MB bf16 intermediates
  ushort_t* Qw = (ushort_t*)d_ws;              // [4096, 3072] bf16
  ushort_t* Kw = Qw + (size_t)4096 * 3072;     // [4096, 1024]
  ushort_t* Vw = Kw + (size_t)4096 * 1024;     // [4096, 1024]
  ushort_t* Cw = Vw + (size_t)4096 * 1024;     // [4096, 3072] ctx

  dim3 blk(256);
  gemm_f32_bt_kernel<<<dim3(24, 32), blk, 0, stream>>>(hs, Wq, bq, Qw, 3072, 3072);
  gemm_f32_bt_kernel<<<dim3(8, 32), blk, 0, stream>>>(hs, Wk, bk, Kw, 1024, 3072);
  gemm_f32_bt_kernel<<<dim3(8, 32), blk, 0, stream>>>(hs, Wv, bv, Vw, 1024, 3072);
  attn_kernel<<<dim3(32, 48), blk, 0, stream>>>(Qw, Kw, Vw, Cw);
  gemm_out_kernel<<<dim3(24, 32), blk, 0, stream>>>(Cw, Wd, bd, out, 3072, 3072);
}

// Round 5
// 569.387 us; speedup vs baseline: 1.4941x; 1.4941x over previous
//
#include <hip/hip_runtime.h>

typedef unsigned short ushort_t;
typedef unsigned int uint32;
typedef __bf16 bf16x8 __attribute__((ext_vector_type(8)));
typedef float f32x4 __attribute__((ext_vector_type(4)));

#define MFMA16(a, b, c) __builtin_amdgcn_mfma_f32_16x16x32_bf16((a), (b), (c), 0, 0, 0)

__device__ __forceinline__ ushort_t f2bf(float f) {
  union { float f; uint32 u; } c; c.f = f;
  uint32 u = c.u;
  u += 0x7fffu + ((u >> 16) & 1u);   // round-to-nearest-even
  return (ushort_t)(u >> 16);
}

// async global->LDS, 16B per lane. LDS dest must be wave-uniform base + lane*16.
__device__ __forceinline__ void gload_lds16(const void* g, void* l) {
  __builtin_amdgcn_global_load_lds(
      (const __attribute__((address_space(1))) void*)g,
      (__attribute__((address_space(3))) void*)l, 16, 0, 0);
}

// ---------------------------------------------------------------------------
// fp32 -> bf16 convert, vectorized: float4 load, 8B store. n % 4 == 0.
// ---------------------------------------------------------------------------
__global__ __launch_bounds__(256)
void cvt_kernel(const float* __restrict__ in, ushort_t* __restrict__ out, int n) {
  int i = (blockIdx.x * 256 + threadIdx.x) * 4;
  const int stride = gridDim.x * 256 * 4;
  for (; i < n; i += stride) {
    float4 v = *(const float4*)(in + i);
    union { uint2 u; ushort_t s[4]; } p;
    p.s[0] = f2bf(v.x); p.s[1] = f2bf(v.y);
    p.s[2] = f2bf(v.z); p.s[3] = f2bf(v.w);
    *(uint2*)(out + i) = p.u;
  }
}

// ---------------------------------------------------------------------------
// C[M,N] = A[M,K] @ W[N,K]^T + bias[N]. A,W bf16; bias fp32; fp32 accum.
// m97 structure: 128x128 tile, BK=32, 4 waves (2x2), global_load_lds width 16.
// OUT_F32: write C as fp32 (for d_out), else bf16. XCD-swizzled block ids.
// grid = (N/128)*(M/128) linear, block = 256.
// ---------------------------------------------------------------------------
template <bool OUT_F32>
__global__ __launch_bounds__(256)
void gemm_bt_kernel(const ushort_t* __restrict__ A, const ushort_t* __restrict__ W,
                    const float* __restrict__ bias, void* __restrict__ Cv,
                    int N, int Kd, int gx)
{
  __shared__ __attribute__((aligned(16))) ushort_t As[128 * 32];
  __shared__ __attribute__((aligned(16))) ushort_t Bs[128 * 32];
  const int tid = threadIdx.x;
  const int lane = tid & 63;
  const int wv = tid >> 6;
  const int wr = wv >> 1, wc = wv & 1;
  // XCD-aware swizzle (nwg % 8 == 0 for all our grids)
  const int nwg = gridDim.x;
  const int cpx = nwg >> 3;
  const int fid = (blockIdx.x & 7) * cpx + (blockIdx.x >> 3);
  const int bn = fid % gx, bm = fid / gx;
  const int l15 = lane & 15, lg = lane >> 4;

  f32x4 acc[4][4] = {};
  const int nk = Kd >> 5;
  const size_t rowA0 = (size_t)bm * 128;
  const size_t rowB0 = (size_t)bn * 128;

  for (int kt = 0; kt < nk; ++kt) {
#pragma unroll
    for (int i = 0; i < 2; ++i) {
      int o = (i * 256 + tid) * 16;   // LDS byte offset
      int row = o >> 6;               // 64B per row (32 bf16)
      int cb = o & 63;
      gload_lds16(A + (rowA0 + row) * Kd + kt * 32 + (cb >> 1), (char*)As + o);
      gload_lds16(W + (rowB0 + row) * Kd + kt * 32 + (cb >> 1), (char*)Bs + o);
    }
    __syncthreads();
    bf16x8 af[4], bfr[4];
#pragma unroll
    for (int mi = 0; mi < 4; ++mi)
      af[mi] = *(const bf16x8*)&As[(wr * 64 + mi * 16 + l15) * 32 + lg * 8];
#pragma unroll
    for (int nj = 0; nj < 4; ++nj)
      bfr[nj] = *(const bf16x8*)&Bs[(wc * 64 + nj * 16 + l15) * 32 + lg * 8];
#pragma unroll
    for (int mi = 0; mi < 4; ++mi)
#pragma unroll
      for (int nj = 0; nj < 4; ++nj)
        acc[mi][nj] = MFMA16(af[mi], bfr[nj], acc[mi][nj]);
    __syncthreads();
  }

  // epilogue: C/D layout row=(lg*4+r), col=l15 within each 16x16 frag
#pragma unroll
  for (int nj = 0; nj < 4; ++nj) {
    int col = bn * 128 + wc * 64 + nj * 16 + l15;
    float bv = bias[col];
#pragma unroll
    for (int mi = 0; mi < 4; ++mi) {
      int row0 = bm * 128 + wr * 64 + mi * 16 + lg * 4;
#pragma unroll
      for (int r = 0; r < 4; ++r) {
        float v = acc[mi][nj][r] + bv;
        if (OUT_F32)
          ((float*)Cv)[(size_t)(row0 + r) * N + col] = v;
        else
          ((ushort_t*)Cv)[(size_t)(row0 + r) * N + col] = f2bf(v);
      }
    }
  }
}

// ---------------------------------------------------------------------------
// Flash attention, causal, GQA. Q/ctx: [B*S, 3072] (col = h*128+d),
// K/V: [B*S, 1024] (col = kvh*128+d). grid = (16 pairs, B*NH), block = 256.
// Block p handles qb = p AND qb = 31-p (uniform 33 K-tiles total).
// Wave w owns q rows [q0+16w, q0+16w+16). KV tiles of 64 staged in LDS.
// ---------------------------------------------------------------------------
#define NHEADS 24
#define GRP 3
#define SEQ 2048
#define SCALE 0.08838834764831845f
#define PSTR 88   // P-buffer stride in elements: 176B = 16B-aligned, 2-way bank (free)

__global__ __launch_bounds__(256)
void attn_kernel(const ushort_t* __restrict__ Q, const ushort_t* __restrict__ K,
                 const ushort_t* __restrict__ V, ushort_t* __restrict__ O)
{
  __shared__ __attribute__((aligned(16))) ushort_t Kl[64 * 128];     // swizzled [kv][d]
  __shared__ __attribute__((aligned(16))) ushort_t Vt[128 * 64];     // swizzled [d][kv]
  __shared__ __attribute__((aligned(16))) ushort_t Pl[4][16 * PSTR]; // per-wave P

  const int tid = threadIdx.x;
  const int lane = tid & 63;
  const int wv = tid >> 6;
  const int l15 = lane & 15, lg = lane >> 4;
  const int pr = blockIdx.x;
  const int bh = blockIdx.y;
  const int b = bh / NHEADS, h = bh % NHEADS;
  const int kvh = h / GRP;
  const size_t kbase = (size_t)b * SEQ * 1024 + (size_t)kvh * 128;

  for (int pass = 0; pass < 2; ++pass) {
    const int qb = pass ? (31 - pr) : pr;
    const int q0 = qb * 64;

    // Q fragments in registers: rows q0+wv*16+l15, d chunks of 32
    bf16x8 qf[4];
    {
      const ushort_t* qg = Q + (size_t)(b * SEQ + q0 + wv * 16 + l15) * 3072 + h * 128 + lg * 8;
#pragma unroll
      for (int c = 0; c < 4; ++c) qf[c] = *(const bf16x8*)(qg + c * 32);
    }

    float m_st[4], l_st[4];
#pragma unroll
    for (int r = 0; r < 4; ++r) { m_st[r] = -1e30f; l_st[r] = 0.f; }
    f32x4 accO[8] = {};

    for (int t = 0; t <= qb; ++t) {
      const int kv0 = t * 64;
      // ---- stage K tile, swizzle via pre-swizzled global source ----
#pragma unroll
      for (int i = 0; i < 4; ++i) {
        int o = (i * 256 + tid) * 16;   // LDS byte offset, 256B per kv row
        int row = o >> 8;
        int within = o & 255;
        int src = within ^ ((row & 7) << 4);
        gload_lds16(K + kbase + (size_t)(kv0 + row) * 1024 + (src >> 1), (char*)Kl + o);
      }
      // ---- stage V transposed: Vt[d][kv], swizzled ----
      {
        int kvr = tid & 63;
        int d0 = (tid >> 6) * 32;
        const ushort_t* vg = V + kbase + (size_t)(kv0 + kvr) * 1024 + d0;
#pragma unroll
        for (int cc = 0; cc < 4; ++cc) {
          union { uint4 u; ushort_t s[8]; } vvv;
          vvv.u = *(const uint4*)(vg + cc * 8);
#pragma unroll
          for (int e = 0; e < 8; ++e) {
            int d = d0 + cc * 8 + e;
            int off = (d * 128 + kvr * 2) ^ ((d & 7) << 4);
            *(ushort_t*)((char*)Vt + off) = vvv.s[e];
          }
        }
      }
      __syncthreads();

      // ---- scores: S[16q][64kv] per wave, 4 col-frags x 4 d-chunks ----
      f32x4 s[4];
#pragma unroll
      for (int n = 0; n < 4; ++n) {
        f32x4 z = {0.f, 0.f, 0.f, 0.f};
        s[n] = z;
#pragma unroll
        for (int c = 0; c < 4; ++c) {
          int row = n * 16 + l15;
          int boff = (row * 256 + c * 64 + lg * 16) ^ ((row & 7) << 4);
          bf16x8 kf = *(const bf16x8*)((const char*)Kl + boff);
          s[n] = MFMA16(qf[c], kf, s[n]);
        }
      }

      // scale + causal mask (only diagonal tile has masked entries)
      if (t == qb) {
#pragma unroll
        for (int n = 0; n < 4; ++n)
#pragma unroll
          for (int r = 0; r < 4; ++r) {
            int kvc = n * 16 + l15;
            int qr = wv * 16 + lg * 4 + r;
            s[n][r] = (kvc > qr) ? -1e9f : s[n][r] * SCALE;
          }
      } else {
#pragma unroll
        for (int n = 0; n < 4; ++n)
#pragma unroll
          for (int r = 0; r < 4; ++r) s[n][r] *= SCALE;
      }

      // online softmax: row (q = lg*4+r) lives on the 16 consecutive lanes of group lg
      float mnew[4], alpha[4], rsum[4];
#pragma unroll
      for (int r = 0; r < 4; ++r) {
        float mx = fmaxf(fmaxf(s[0][r], s[1][r]), fmaxf(s[2][r], s[3][r]));
#pragma unroll
        for (int off = 1; off < 16; off <<= 1)
          mx = fmaxf(mx, __shfl_xor(mx, off, 64));
        mnew[r] = fmaxf(m_st[r], mx);
        alpha[r] = __expf(m_st[r] - mnew[r]);
        m_st[r] = mnew[r];
        rsum[r] = 0.f;
      }

      ushort_t* Pw = &Pl[wv][0];
#pragma unroll
      for (int n = 0; n < 4; ++n)
#pragma unroll
        for (int r = 0; r < 4; ++r) {
          float p = __expf(s[n][r] - mnew[r]);
          rsum[r] += p;
          Pw[(lg * 4 + r) * PSTR + n * 16 + l15] = f2bf(p);
        }
#pragma unroll
      for (int r = 0; r < 4; ++r) {
        float sm = rsum[r];
#pragma unroll
        for (int off = 1; off < 16; off <<= 1)
          sm += __shfl_xor(sm, off, 64);
        l_st[r] = l_st[r] * alpha[r] + sm;
      }

      // rescale running O
#pragma unroll
      for (int j = 0; j < 8; ++j)
#pragma unroll
        for (int r = 0; r < 4; ++r) accO[j][r] *= alpha[r];

      // ---- PV: O[16q][128d] += P[16q][64kv] @ V[64kv][128d] ----
#pragma unroll
      for (int c = 0; c < 2; ++c) {
        bf16x8 pa = *(const bf16x8*)&Pw[l15 * PSTR + c * 32 + lg * 8];
#pragma unroll
        for (int j = 0; j < 8; ++j) {
          int d = j * 16 + l15;
          int off = (d * 128 + c * 64 + lg * 16) ^ ((d & 7) << 4);
          bf16x8 vf = *(const bf16x8*)((const char*)Vt + off);
          accO[j] = MFMA16(pa, vf, accO[j]);
        }
      }
      __syncthreads();
    }

    // epilogue: normalize and store ctx (global only — no LDS hazard with next pass)
    float inv[4];
#pragma unroll
    for (int r = 0; r < 4; ++r) inv[r] = 1.0f / l_st[r];
    ushort_t* og = O + (size_t)(b * SEQ + q0 + wv * 16 + lg * 4) * 3072 + h * 128 + l15;
#pragma unroll
    for (int j = 0; j < 8; ++j)
#pragma unroll
      for (int r = 0; r < 4; ++r)
        og[(size_t)r * 3072 + j * 16] = f2bf(accO[j][r] * inv[r]);
  }
}

// ---------------------------------------------------------------------------
extern "C" void kernel_launch(void* const* d_in, const int* in_sizes, int n_in,
                              void* d_out, int out_size, void* d_ws, size_t ws_size,
                              hipStream_t stream) {
  // Inputs fp32; output fp32 (reference output dtype). Intermediates bf16 in ws.
  const float* hs = (const float*)d_in[0];
  // d_in[1] = attention_mask (causal by construction; applied analytically)
  const float* Wq = (const float*)d_in[2];
  const float* bq = (const float*)d_in[3];
  const float* Wk = (const float*)d_in[4];
  const float* bk = (const float*)d_in[5];
  const float* Wv = (const float*)d_in[6];
  const float* bv = (const float*)d_in[7];
  const float* Wd = (const float*)d_in[8];
  const float* bd = (const float*)d_in[9];
  float* out = (float*)d_out;

  const size_t N_HS = (size_t)4096 * 3072;
  const size_t N_WQ = (size_t)3072 * 3072;
  const size_t N_WK = (size_t)1024 * 3072;

  // ws layout (117.4 MB total — proven safe: rounds 2/3 bit-identical outputs)
  ushort_t* hs_bf = (ushort_t*)d_ws;
  ushort_t* Wq_bf = hs_bf + N_HS;
  ushort_t* Wk_bf = Wq_bf + N_WQ;
  ushort_t* Wv_bf = Wk_bf + N_WK;
  ushort_t* Wd_bf = Wv_bf + N_WK;
  ushort_t* Qw    = Wd_bf + N_WQ;             // [4096, 3072]
  ushort_t* Kw    = Qw + N_HS;                // [4096, 1024]
  ushort_t* Vw    = Kw + (size_t)4096 * 1024; // [4096, 1024]
  ushort_t* Cw    = hs_bf;                    // ctx aliases hs_bf (dead after V GEMM)

  dim3 blk(256);
  cvt_kernel<<<2048, blk, 0, stream>>>(hs, hs_bf, (int)N_HS);
  cvt_kernel<<<2048, blk, 0, stream>>>(Wq, Wq_bf, (int)N_WQ);
  cvt_kernel<<<1024, blk, 0, stream>>>(Wk, Wk_bf, (int)N_WK);
  cvt_kernel<<<1024, blk, 0, stream>>>(Wv, Wv_bf, (int)N_WK);
  cvt_kernel<<<2048, blk, 0, stream>>>(Wd, Wd_bf, (int)N_WQ);

  gemm_bt_kernel<false><<<dim3(24 * 32), blk, 0, stream>>>(hs_bf, Wq_bf, bq, Qw, 3072, 3072, 24);
  gemm_bt_kernel<false><<<dim3(8 * 32), blk, 0, stream>>>(hs_bf, Wk_bf, bk, Kw, 1024, 3072, 8);
  gemm_bt_kernel<false><<<dim3(8 * 32), blk, 0, stream>>>(hs_bf, Wv_bf, bv, Vw, 1024, 3072, 8);
  attn_kernel<<<dim3(16, 48), blk, 0, stream>>>(Qw, Kw, Vw, Cw);
  gemm_bt_kernel<true><<<dim3(24 * 32), blk, 0, stream>>>(Cw, Wd_bf, bd, out, 3072, 3072, 24);
}

// Round 6
// 530.550 us; speedup vs baseline: 1.6034x; 1.0732x over previous
//
#include <hip/hip_runtime.h>

typedef unsigned short ushort_t;
typedef unsigned int uint32;
typedef __bf16 bf16x8 __attribute__((ext_vector_type(8)));
typedef float f32x4 __attribute__((ext_vector_type(4)));

#define MFMA16(a, b, c) __builtin_amdgcn_mfma_f32_16x16x32_bf16((a), (b), (c), 0, 0, 0)

__device__ __forceinline__ ushort_t f2bf(float f) {
  union { float f; uint32 u; } c; c.f = f;
  uint32 u = c.u;
  u += 0x7fffu + ((u >> 16) & 1u);   // round-to-nearest-even
  return (ushort_t)(u >> 16);
}

// async global->LDS, 16B per lane. LDS dest must be wave-uniform base + lane*16.
__device__ __forceinline__ void gload_lds16(const void* g, void* l) {
  __builtin_amdgcn_global_load_lds(
      (const __attribute__((address_space(1))) void*)g,
      (__attribute__((address_space(3))) void*)l, 16, 0, 0);
}

// ---------------------------------------------------------------------------
// fp32 -> bf16 convert, vectorized: float4 load, 8B store. n % 4 == 0.
// ---------------------------------------------------------------------------
__global__ __launch_bounds__(256)
void cvt_kernel(const float* __restrict__ in, ushort_t* __restrict__ out, int n) {
  int i = (blockIdx.x * 256 + threadIdx.x) * 4;
  const int stride = gridDim.x * 256 * 4;
  for (; i < n; i += stride) {
    float4 v = *(const float4*)(in + i);
    union { uint2 u; ushort_t s[4]; } p;
    p.s[0] = f2bf(v.x); p.s[1] = f2bf(v.y);
    p.s[2] = f2bf(v.z); p.s[3] = f2bf(v.w);
    *(uint2*)(out + i) = p.u;
  }
}

// ===========================================================================
// Shared GEMM tile body: 128x128 tile, BK=64, 4 waves (2x2), 4x4 frags/wave.
// LDS rows are 128B -> XOR-swizzle (row&7)<<4 via pre-swizzled gload source
// (same pattern as attn K staging, proven rounds 2-5).
// ===========================================================================
#define GEMM_BODY(ABASE, WROWBASE, KD)                                          \
  f32x4 acc[4][4] = {};                                                         \
  const int nk = (KD) >> 6;                                                     \
  for (int kt = 0; kt < nk; ++kt) {                                             \
    _Pragma("unroll")                                                           \
    for (int i = 0; i < 4; ++i) {                                               \
      int o = (i * 256 + tid) * 16;                                             \
      int row = o >> 7;                                                         \
      int src = (o & 127) ^ ((row & 7) << 4);                                   \
      gload_lds16(ABASE + (rowA0 + row) * (KD) + kt * 64 + (src >> 1),          \
                  (char*)As + o);                                               \
      gload_lds16(WROWBASE + (size_t)row * (KD) + kt * 64 + (src >> 1),         \
                  (char*)Bs + o);                                               \
    }                                                                           \
    __syncthreads();                                                            \
    bf16x8 af[4][2], bfr[4][2];                                                 \
    _Pragma("unroll")                                                           \
    for (int mi = 0; mi < 4; ++mi) {                                            \
      int row = wr * 64 + mi * 16 + l15;                                        \
      _Pragma("unroll")                                                         \
      for (int kk = 0; kk < 2; ++kk) {                                          \
        int boff = (row * 128 + kk * 64 + lg * 16) ^ ((row & 7) << 4);          \
        af[mi][kk] = *(const bf16x8*)((const char*)As + boff);                  \
      }                                                                         \
    }                                                                           \
    _Pragma("unroll")                                                           \
    for (int nj = 0; nj < 4; ++nj) {                                            \
      int row = wc * 64 + nj * 16 + l15;                                        \
      _Pragma("unroll")                                                         \
      for (int kk = 0; kk < 2; ++kk) {                                          \
        int boff = (row * 128 + kk * 64 + lg * 16) ^ ((row & 7) << 4);          \
        bfr[nj][kk] = *(const bf16x8*)((const char*)Bs + boff);                 \
      }                                                                         \
    }                                                                           \
    _Pragma("unroll")                                                           \
    for (int mi = 0; mi < 4; ++mi)                                              \
      _Pragma("unroll")                                                         \
      for (int nj = 0; nj < 4; ++nj)                                            \
        _Pragma("unroll")                                                       \
        for (int kk = 0; kk < 2; ++kk)                                          \
          acc[mi][nj] = MFMA16(af[mi][kk], bfr[nj][kk], acc[mi][nj]);           \
    __syncthreads();                                                            \
  }

// ---------------------------------------------------------------------------
// Fused QKV GEMM: C[4096,5120] = hs @ [Wq;Wk;Wv]^T + [bq;bk;bv].
// cols 0..3071 = Q, 3072..4095 = K, 4096..5119 = V. grid = 1280 (40x32).
// ---------------------------------------------------------------------------
__global__ __launch_bounds__(256)
void qkv_gemm_kernel(const ushort_t* __restrict__ A,
                     const ushort_t* __restrict__ Wq, const ushort_t* __restrict__ Wk,
                     const ushort_t* __restrict__ Wv,
                     const float* __restrict__ bq, const float* __restrict__ bk,
                     const float* __restrict__ bv, ushort_t* __restrict__ C)
{
  __shared__ __attribute__((aligned(16))) ushort_t As[128 * 64];
  __shared__ __attribute__((aligned(16))) ushort_t Bs[128 * 64];
  const int tid = threadIdx.x;
  const int lane = tid & 63;
  const int wv_ = tid >> 6;
  const int wr = wv_ >> 1, wc = wv_ & 1;
  const int fid = (blockIdx.x & 7) * 160 + (blockIdx.x >> 3);  // XCD swizzle, 1280 wgs
  const int bn = fid % 40, bm = fid / 40;
  const int l15 = lane & 15, lg = lane >> 4;

  const ushort_t* Wsrc; const float* bsrc; int nloc;
  if (bn < 24)      { Wsrc = Wq; bsrc = bq; nloc = bn << 7; }
  else if (bn < 32) { Wsrc = Wk; bsrc = bk; nloc = (bn - 24) << 7; }
  else              { Wsrc = Wv; bsrc = bv; nloc = (bn - 32) << 7; }

  const size_t rowA0 = (size_t)bm * 128;
  const ushort_t* Wrow = Wsrc + (size_t)nloc * 3072;

  GEMM_BODY(A, Wrow, 3072)

#pragma unroll
  for (int nj = 0; nj < 4; ++nj) {
    int cl = wc * 64 + nj * 16 + l15;
    float bvl = bsrc[nloc + cl];
    int col = bn * 128 + cl;
#pragma unroll
    for (int mi = 0; mi < 4; ++mi) {
      int row0 = bm * 128 + wr * 64 + mi * 16 + lg * 4;
#pragma unroll
      for (int r = 0; r < 4; ++r)
        C[(size_t)(row0 + r) * 5120 + col] = f2bf(acc[mi][nj][r] + bvl);
    }
  }
}

// ---------------------------------------------------------------------------
// Generic single-weight GEMM (used for out-proj): C = A @ W^T + bias.
// OUT_F32 selects fp32 output. grid = gx * (M/128) linear, XCD-swizzled.
// ---------------------------------------------------------------------------
template <bool OUT_F32>
__global__ __launch_bounds__(256)
void gemm_bt_kernel(const ushort_t* __restrict__ A, const ushort_t* __restrict__ W,
                    const float* __restrict__ bias, void* __restrict__ Cv,
                    int N, int Kd, int gx)
{
  __shared__ __attribute__((aligned(16))) ushort_t As[128 * 64];
  __shared__ __attribute__((aligned(16))) ushort_t Bs[128 * 64];
  const int tid = threadIdx.x;
  const int lane = tid & 63;
  const int wv_ = tid >> 6;
  const int wr = wv_ >> 1, wc = wv_ & 1;
  const int nwg = gridDim.x;
  const int cpx = nwg >> 3;
  const int fid = (blockIdx.x & 7) * cpx + (blockIdx.x >> 3);
  const int bn = fid % gx, bm = fid / gx;
  const int l15 = lane & 15, lg = lane >> 4;

  const size_t rowA0 = (size_t)bm * 128;
  const ushort_t* Wrow = W + (size_t)(bn * 128) * Kd;

  GEMM_BODY(A, Wrow, Kd)

#pragma unroll
  for (int nj = 0; nj < 4; ++nj) {
    int col = bn * 128 + wc * 64 + nj * 16 + l15;
    float bvl = bias[col];
#pragma unroll
    for (int mi = 0; mi < 4; ++mi) {
      int row0 = bm * 128 + wr * 64 + mi * 16 + lg * 4;
#pragma unroll
      for (int r = 0; r < 4; ++r) {
        float v = acc[mi][nj][r] + bvl;
        if (OUT_F32) ((float*)Cv)[(size_t)(row0 + r) * N + col] = v;
        else         ((ushort_t*)Cv)[(size_t)(row0 + r) * N + col] = f2bf(v);
      }
    }
  }
}

// ---------------------------------------------------------------------------
// Flash attention, causal, GQA. QKV combined: [B*S, 5120] (Q col h*128+d,
// K col 3072+kvh*128+d, V col 4096+kvh*128+d). ctx out: [B*S, 3072].
// grid = (16 pairs, B*NH), block = 256; block p does qb = p and 31-p.
// SCALE*log2e folded into Q; exp2-domain online softmax.
// ---------------------------------------------------------------------------
#define NHEADS 24
#define GRP 3
#define SEQ 2048
#define QSCL 0.12751745f   // HD^-0.5 * log2(e)
#define PSTR 88            // P stride: 176B, 16B-aligned, 2-way bank (free)

__global__ __launch_bounds__(256)
void attn_kernel(const ushort_t* __restrict__ QKV, ushort_t* __restrict__ O)
{
  __shared__ __attribute__((aligned(16))) ushort_t Kl[64 * 128];     // swizzled [kv][d]
  __shared__ __attribute__((aligned(16))) ushort_t Vt[128 * 64];     // swizzled [d][kv]
  __shared__ __attribute__((aligned(16))) ushort_t Pl[4][16 * PSTR]; // per-wave P

  const int tid = threadIdx.x;
  const int lane = tid & 63;
  const int wv = tid >> 6;
  const int l15 = lane & 15, lg = lane >> 4;
  const int pr = blockIdx.x;
  const int bh = blockIdx.y;
  const int b = bh / NHEADS, h = bh % NHEADS;
  const int kvh = h / GRP;
  const size_t kbase = (size_t)b * SEQ * 5120 + 3072 + (size_t)kvh * 128;
  const size_t vbase = kbase + 1024;

  for (int pass = 0; pass < 2; ++pass) {
    const int qb = pass ? (31 - pr) : pr;
    const int q0 = qb * 64;

    // Q fragments in registers, pre-scaled by SCALE*log2e
    bf16x8 qf[4];
    {
      const ushort_t* qg = QKV + (size_t)(b * SEQ + q0 + wv * 16 + l15) * 5120 + h * 128 + lg * 8;
#pragma unroll
      for (int c = 0; c < 4; ++c) {
        bf16x8 q = *(const bf16x8*)(qg + c * 32);
#pragma unroll
        for (int e = 0; e < 8; ++e) q[e] = (__bf16)((float)q[e] * QSCL);
        qf[c] = q;
      }
    }

    float m_st[4], l_st[4];
#pragma unroll
    for (int r = 0; r < 4; ++r) { m_st[r] = -1e30f; l_st[r] = 0.f; }
    f32x4 accO[8] = {};

    for (int t = 0; t <= qb; ++t) {
      const int kv0 = t * 64;
      // ---- stage K tile via gload_lds, pre-swizzled source ----
#pragma unroll
      for (int i = 0; i < 4; ++i) {
        int o = (i * 256 + tid) * 16;   // 256B per kv row
        int row = o >> 8;
        int src = (o & 255) ^ ((row & 7) << 4);
        gload_lds16(QKV + kbase + (size_t)(kv0 + row) * 5120 + (src >> 1), (char*)Kl + o);
      }
      // ---- stage V transposed: thread owns 4 kv x 8 d; b64 writes ----
      {
        int kv4 = (tid & 15) * 4;
        int d8 = (tid >> 4) * 8;
        const ushort_t* vg = QKV + vbase + (size_t)(kv0 + kv4) * 5120 + d8;
        union { uint4 u; ushort_t s[8]; } L0, L1, L2, L3;
        L0.u = *(const uint4*)(vg);
        L1.u = *(const uint4*)(vg + 5120);
        L2.u = *(const uint4*)(vg + 10240);
        L3.u = *(const uint4*)(vg + 15360);
#pragma unroll
        for (int dd = 0; dd < 8; ++dd) {
          int d = d8 + dd;
          uint2 w;
          w.x = (uint32)L0.s[dd] | ((uint32)L1.s[dd] << 16);
          w.y = (uint32)L2.s[dd] | ((uint32)L3.s[dd] << 16);
          int off = (d * 128 + kv4 * 2) ^ ((d & 7) << 4);
          *(uint2*)((char*)Vt + off) = w;
        }
      }
      __syncthreads();

      // ---- scores: S[16q][64kv] per wave (exp2 domain) ----
      f32x4 s[4];
      __builtin_amdgcn_s_setprio(1);
#pragma unroll
      for (int n = 0; n < 4; ++n) {
        f32x4 z = {0.f, 0.f, 0.f, 0.f};
        s[n] = z;
#pragma unroll
        for (int c = 0; c < 4; ++c) {
          int row = n * 16 + l15;
          int boff = (row * 256 + c * 64 + lg * 16) ^ ((row & 7) << 4);
          bf16x8 kf = *(const bf16x8*)((const char*)Kl + boff);
          s[n] = MFMA16(qf[c], kf, s[n]);
        }
      }
      __builtin_amdgcn_s_setprio(0);

      // causal mask on diagonal tile only (scale already folded into Q)
      if (t == qb) {
#pragma unroll
        for (int n = 0; n < 4; ++n)
#pragma unroll
          for (int r = 0; r < 4; ++r) {
            int kvc = n * 16 + l15;
            int qr = wv * 16 + lg * 4 + r;
            if (kvc > qr) s[n][r] = -1e9f;
          }
      }

      // online softmax (exp2 domain): row q=lg*4+r on the 16 lanes of group lg
      float mnew[4], alpha[4], rsum[4];
#pragma unroll
      for (int r = 0; r < 4; ++r) {
        float mx = fmaxf(fmaxf(s[0][r], s[1][r]), fmaxf(s[2][r], s[3][r]));
#pragma unroll
        for (int off = 1; off < 16; off <<= 1)
          mx = fmaxf(mx, __shfl_xor(mx, off, 64));
        mnew[r] = fmaxf(m_st[r], mx);
        alpha[r] = __builtin_amdgcn_exp2f(m_st[r] - mnew[r]);
        m_st[r] = mnew[r];
        rsum[r] = 0.f;
      }

      ushort_t* Pw = &Pl[wv][0];
#pragma unroll
      for (int n = 0; n < 4; ++n)
#pragma unroll
        for (int r = 0; r < 4; ++r) {
          float p = __builtin_amdgcn_exp2f(s[n][r] - mnew[r]);
          rsum[r] += p;
          Pw[(lg * 4 + r) * PSTR + n * 16 + l15] = f2bf(p);
        }
#pragma unroll
      for (int r = 0; r < 4; ++r) {
        float sm = rsum[r];
#pragma unroll
        for (int off = 1; off < 16; off <<= 1)
          sm += __shfl_xor(sm, off, 64);
        l_st[r] = l_st[r] * alpha[r] + sm;
      }

      // rescale running O
#pragma unroll
      for (int j = 0; j < 8; ++j)
#pragma unroll
        for (int r = 0; r < 4; ++r) accO[j][r] *= alpha[r];

      // ---- PV: O[16q][128d] += P[16q][64kv] @ V[64kv][128d] ----
      __builtin_amdgcn_s_setprio(1);
#pragma unroll
      for (int c = 0; c < 2; ++c) {
        bf16x8 pa = *(const bf16x8*)&Pw[l15 * PSTR + c * 32 + lg * 8];
#pragma unroll
        for (int j = 0; j < 8; ++j) {
          int d = j * 16 + l15;
          int off = (d * 128 + c * 64 + lg * 16) ^ ((d & 7) << 4);
          bf16x8 vf = *(const bf16x8*)((const char*)Vt + off);
          accO[j] = MFMA16(pa, vf, accO[j]);
        }
      }
      __builtin_amdgcn_s_setprio(0);
      __syncthreads();
    }

    // epilogue: normalize and store ctx
    float inv[4];
#pragma unroll
    for (int r = 0; r < 4; ++r) inv[r] = 1.0f / l_st[r];
    ushort_t* og = O + (size_t)(b * SEQ + q0 + wv * 16 + lg * 4) * 3072 + h * 128 + l15;
#pragma unroll
    for (int j = 0; j < 8; ++j)
#pragma unroll
      for (int r = 0; r < 4; ++r)
        og[(size_t)r * 3072 + j * 16] = f2bf(accO[j][r] * inv[r]);
  }
}

// ---------------------------------------------------------------------------
extern "C" void kernel_launch(void* const* d_in, const int* in_sizes, int n_in,
                              void* d_out, int out_size, void* d_ws, size_t ws_size,
                              hipStream_t stream) {
  const float* hs = (const float*)d_in[0];
  // d_in[1] = attention_mask (causal by construction; applied analytically)
  const float* Wq = (const float*)d_in[2];
  const float* bq = (const float*)d_in[3];
  const float* Wk = (const float*)d_in[4];
  const float* bk = (const float*)d_in[5];
  const float* Wv = (const float*)d_in[6];
  const float* bv = (const float*)d_in[7];
  const float* Wd = (const float*)d_in[8];
  const float* bd = (const float*)d_in[9];
  float* out = (float*)d_out;

  const size_t N_HS = (size_t)4096 * 3072;
  const size_t N_WQ = (size_t)3072 * 3072;
  const size_t N_WK = (size_t)1024 * 3072;

  // ws layout: 117.4 MB (same total as round 5 — proven safe)
  ushort_t* hs_bf = (ushort_t*)d_ws;
  ushort_t* Wq_bf = hs_bf + N_HS;
  ushort_t* Wk_bf = Wq_bf + N_WQ;
  ushort_t* Wv_bf = Wk_bf + N_WK;
  ushort_t* Wd_bf = Wv_bf + N_WK;
  ushort_t* QKVw  = Wd_bf + N_WQ;            // [4096, 5120]
  ushort_t* Cw    = hs_bf;                   // ctx aliases hs_bf (dead after QKV GEMM)

  dim3 blk(256);
  cvt_kernel<<<2048, blk, 0, stream>>>(hs, hs_bf, (int)N_HS);
  cvt_kernel<<<2048, blk, 0, stream>>>(Wq, Wq_bf, (int)N_WQ);
  cvt_kernel<<<1024, blk, 0, stream>>>(Wk, Wk_bf, (int)N_WK);
  cvt_kernel<<<1024, blk, 0, stream>>>(Wv, Wv_bf, (int)N_WK);
  cvt_kernel<<<2048, blk, 0, stream>>>(Wd, Wd_bf, (int)N_WQ);

  qkv_gemm_kernel<<<dim3(1280), blk, 0, stream>>>(hs_bf, Wq_bf, Wk_bf, Wv_bf,
                                                  bq, bk, bv, QKVw);
  attn_kernel<<<dim3(16, 48), blk, 0, stream>>>(QKVw, Cw);
  gemm_bt_kernel<true><<<dim3(24 * 32), blk, 0, stream>>>(Cw, Wd_bf, bd, out, 3072, 3072, 24);
}

// Round 7
// 512.729 us; speedup vs baseline: 1.6591x; 1.0348x over previous
//
#include <hip/hip_runtime.h>

typedef unsigned short ushort_t;
typedef unsigned int uint32;
typedef __bf16 bf16x8 __attribute__((ext_vector_type(8)));
typedef float f32x4 __attribute__((ext_vector_type(4)));

#define MFMA16(a, b, c) __builtin_amdgcn_mfma_f32_16x16x32_bf16((a), (b), (c), 0, 0, 0)

__device__ __forceinline__ ushort_t f2bf(float f) {
  union { float f; uint32 u; } c; c.f = f;
  uint32 u = c.u;
  u += 0x7fffu + ((u >> 16) & 1u);   // round-to-nearest-even
  return (ushort_t)(u >> 16);
}

// async global->LDS, 16B per lane. LDS dest must be wave-uniform base + lane*16.
__device__ __forceinline__ void gload_lds16(const void* g, void* l) {
  __builtin_amdgcn_global_load_lds(
      (const __attribute__((address_space(1))) void*)g,
      (__attribute__((address_space(3))) void*)l, 16, 0, 0);
}

// ---------------------------------------------------------------------------
// fp32 -> bf16 convert, vectorized: float4 load, 8B store. n % 4 == 0.
// ---------------------------------------------------------------------------
__global__ __launch_bounds__(256)
void cvt_kernel(const float* __restrict__ in, ushort_t* __restrict__ out, int n) {
  int i = (blockIdx.x * 256 + threadIdx.x) * 4;
  const int stride = gridDim.x * 256 * 4;
  for (; i < n; i += stride) {
    float4 v = *(const float4*)(in + i);
    union { uint2 u; ushort_t s[4]; } p;
    p.s[0] = f2bf(v.x); p.s[1] = f2bf(v.y);
    p.s[2] = f2bf(v.z); p.s[3] = f2bf(v.w);
    *(uint2*)(out + i) = p.u;
  }
}

// ===========================================================================
// Shared GEMM tile body (unchanged from round 6): 128x128, BK=64, 4 waves.
// ===========================================================================
#define GEMM_BODY(ABASE, WROWBASE, KD)                                          \
  f32x4 acc[4][4] = {};                                                         \
  const int nk = (KD) >> 6;                                                     \
  for (int kt = 0; kt < nk; ++kt) {                                             \
    _Pragma("unroll")                                                           \
    for (int i = 0; i < 4; ++i) {                                               \
      int o = (i * 256 + tid) * 16;                                             \
      int row = o >> 7;                                                         \
      int src = (o & 127) ^ ((row & 7) << 4);                                   \
      gload_lds16(ABASE + (rowA0 + row) * (KD) + kt * 64 + (src >> 1),          \
                  (char*)As + o);                                               \
      gload_lds16(WROWBASE + (size_t)row * (KD) + kt * 64 + (src >> 1),         \
                  (char*)Bs + o);                                               \
    }                                                                           \
    __syncthreads();                                                            \
    bf16x8 af[4][2], bfr[4][2];                                                 \
    _Pragma("unroll")                                                           \
    for (int mi = 0; mi < 4; ++mi) {                                            \
      int row = wr * 64 + mi * 16 + l15;                                        \
      _Pragma("unroll")                                                         \
      for (int kk = 0; kk < 2; ++kk) {                                          \
        int boff = (row * 128 + kk * 64 + lg * 16) ^ ((row & 7) << 4);          \
        af[mi][kk] = *(const bf16x8*)((const char*)As + boff);                  \
      }                                                                         \
    }                                                                           \
    _Pragma("unroll")                                                           \
    for (int nj = 0; nj < 4; ++nj) {                                            \
      int row = wc * 64 + nj * 16 + l15;                                        \
      _Pragma("unroll")                                                         \
      for (int kk = 0; kk < 2; ++kk) {                                          \
        int boff = (row * 128 + kk * 64 + lg * 16) ^ ((row & 7) << 4);          \
        bfr[nj][kk] = *(const bf16x8*)((const char*)Bs + boff);                 \
      }                                                                         \
    }                                                                           \
    _Pragma("unroll")                                                           \
    for (int mi = 0; mi < 4; ++mi)                                              \
      _Pragma("unroll")                                                         \
      for (int nj = 0; nj < 4; ++nj)                                            \
        _Pragma("unroll")                                                       \
        for (int kk = 0; kk < 2; ++kk)                                          \
          acc[mi][nj] = MFMA16(af[mi][kk], bfr[nj][kk], acc[mi][nj]);           \
    __syncthreads();                                                            \
  }

// ---------------------------------------------------------------------------
// Fused QKV GEMM (unchanged): C[4096,5120], grid = 1280 (40x32), XCD-swizzled.
// ---------------------------------------------------------------------------
__global__ __launch_bounds__(256)
void qkv_gemm_kernel(const ushort_t* __restrict__ A,
                     const ushort_t* __restrict__ Wq, const ushort_t* __restrict__ Wk,
                     const ushort_t* __restrict__ Wv,
                     const float* __restrict__ bq, const float* __restrict__ bk,
                     const float* __restrict__ bv, ushort_t* __restrict__ C)
{
  __shared__ __attribute__((aligned(16))) ushort_t As[128 * 64];
  __shared__ __attribute__((aligned(16))) ushort_t Bs[128 * 64];
  const int tid = threadIdx.x;
  const int lane = tid & 63;
  const int wv_ = tid >> 6;
  const int wr = wv_ >> 1, wc = wv_ & 1;
  const int fid = (blockIdx.x & 7) * 160 + (blockIdx.x >> 3);
  const int bn = fid % 40, bm = fid / 40;
  const int l15 = lane & 15, lg = lane >> 4;

  const ushort_t* Wsrc; const float* bsrc; int nloc;
  if (bn < 24)      { Wsrc = Wq; bsrc = bq; nloc = bn << 7; }
  else if (bn < 32) { Wsrc = Wk; bsrc = bk; nloc = (bn - 24) << 7; }
  else              { Wsrc = Wv; bsrc = bv; nloc = (bn - 32) << 7; }

  const size_t rowA0 = (size_t)bm * 128;
  const ushort_t* Wrow = Wsrc + (size_t)nloc * 3072;

  GEMM_BODY(A, Wrow, 3072)

#pragma unroll
  for (int nj = 0; nj < 4; ++nj) {
    int cl = wc * 64 + nj * 16 + l15;
    float bvl = bsrc[nloc + cl];
    int col = bn * 128 + cl;
#pragma unroll
    for (int mi = 0; mi < 4; ++mi) {
      int row0 = bm * 128 + wr * 64 + mi * 16 + lg * 4;
#pragma unroll
      for (int r = 0; r < 4; ++r)
        C[(size_t)(row0 + r) * 5120 + col] = f2bf(acc[mi][nj][r] + bvl);
    }
  }
}

// ---------------------------------------------------------------------------
// Generic single-weight GEMM (unchanged, used for out-proj).
// ---------------------------------------------------------------------------
template <bool OUT_F32>
__global__ __launch_bounds__(256)
void gemm_bt_kernel(const ushort_t* __restrict__ A, const ushort_t* __restrict__ W,
                    const float* __restrict__ bias, void* __restrict__ Cv,
                    int N, int Kd, int gx)
{
  __shared__ __attribute__((aligned(16))) ushort_t As[128 * 64];
  __shared__ __attribute__((aligned(16))) ushort_t Bs[128 * 64];
  const int tid = threadIdx.x;
  const int lane = tid & 63;
  const int wv_ = tid >> 6;
  const int wr = wv_ >> 1, wc = wv_ & 1;
  const int nwg = gridDim.x;
  const int cpx = nwg >> 3;
  const int fid = (blockIdx.x & 7) * cpx + (blockIdx.x >> 3);
  const int bn = fid % gx, bm = fid / gx;
  const int l15 = lane & 15, lg = lane >> 4;

  const size_t rowA0 = (size_t)bm * 128;
  const ushort_t* Wrow = W + (size_t)(bn * 128) * Kd;

  GEMM_BODY(A, Wrow, Kd)

#pragma unroll
  for (int nj = 0; nj < 4; ++nj) {
    int col = bn * 128 + wc * 64 + nj * 16 + l15;
    float bvl = bias[col];
#pragma unroll
    for (int mi = 0; mi < 4; ++mi) {
      int row0 = bm * 128 + wr * 64 + mi * 16 + lg * 4;
#pragma unroll
      for (int r = 0; r < 4; ++r) {
        float v = acc[mi][nj][r] + bvl;
        if (OUT_F32) ((float*)Cv)[(size_t)(row0 + r) * N + col] = v;
        else         ((ushort_t*)Cv)[(size_t)(row0 + r) * N + col] = f2bf(v);
      }
    }
  }
}

// ---------------------------------------------------------------------------
// Flash attention v2: swapped QK^T (S^T lane-local), no P_lds, dbuf-K via
// global_load_lds, reg-prefetched V (T14), raw s_barrier + counted waits (T4).
// QKV: [B*S,5120]; ctx out: [B*S,3072]. grid = (B*NH, 16 pairs), block = 256.
// Per wave: 16 q-rows (q = q0+wv*16+l15), 64 kv per tile.
//   QK:  s[n] = mfma(A=K[kv=n*16+l15][d], B=Q[q=l15][d])  -> S^T:
//        lane(l15,lg) reg(n,r) = S[kv=16n+4lg+r][q=l15]   (C: row=lg*4+r,col=l15)
//   softmax over kv = 16 local regs + shfl_xor(16,32)  (q-col is lane-local)
//   PV:  accO[j] = mfma(A=Vt[d=16j+l15][kv], B=P^T[kv][q=l15])
//        B-frag reg j needs kv=c*32+lg*8+j  -> from lane lg''=2*(lg&1)+(j>>2),
//        dword pair n=2c+(lg>>1): 16 ds_bpermute replaces the P LDS round-trip.
// ---------------------------------------------------------------------------
#define NHEADS 24
#define GRP 3
#define SEQ 2048
#define QSCL 0.12751745f   // HD^-0.5 * log2(e)

__global__ __launch_bounds__(256)
void attn_kernel(const ushort_t* __restrict__ QKV, ushort_t* __restrict__ O)
{
  __shared__ __attribute__((aligned(16))) ushort_t Kl[2][64 * 128]; // swizzled [kv][d]
  __shared__ __attribute__((aligned(16))) ushort_t Vt[128 * 64];    // swizzled [d][kv]

  const int tid = threadIdx.x;
  const int lane = tid & 63;
  const int wv = tid >> 6;
  const int l15 = lane & 15, lg = lane >> 4;
  const int bh = blockIdx.x;          // bh fastest => all pr of a head on one XCD
  const int pr = blockIdx.y;
  const int b = bh / NHEADS, h = bh % NHEADS;
  const int kvh = h / GRP;
  const size_t kbase = (size_t)b * SEQ * 5120 + 3072 + (size_t)kvh * 128;
  const size_t vbase = kbase + 1024;

  // V-prefetch addressing: thread owns 4 kv rows x 8 d
  const int kv4 = (tid & 15) * 4;
  const int d8 = (tid >> 4) * 8;
  // P-shuffle source lanes (within-wave): s0 = l15 + 32*(lg&1), s1 = s0+16
  const int psrc0 = (lane & 15) + 32 * (lg & 1) + (wv << 6); // __shfl uses block-lane? no: width 64 => wave-local index
  const int a_sel = lg >> 1;

  for (int pass = 0; pass < 2; ++pass) {
    const int qb = pass ? (31 - pr) : pr;
    const int q0 = qb * 64;

    // ---- prologue: issue K(0) -> Kl[0], V(0) -> regs ----
#pragma unroll
    for (int i = 0; i < 4; ++i) {
      int o = (i * 256 + tid) * 16;
      int row = o >> 8;
      int src = (o & 255) ^ ((row & 7) << 4);
      gload_lds16(QKV + kbase + (size_t)row * 5120 + (src >> 1), (char*)&Kl[0][0] + o);
    }
    uint4 vr0, vr1, vr2, vr3;
    {
      const ushort_t* vg = QKV + vbase + (size_t)kv4 * 5120 + d8;
      vr0 = *(const uint4*)(vg);
      vr1 = *(const uint4*)(vg + 5120);
      vr2 = *(const uint4*)(vg + 10240);
      vr3 = *(const uint4*)(vg + 15360);
    }

    // Q fragments, pre-scaled by SCALE*log2e
    bf16x8 qf[4];
    {
      const ushort_t* qg = QKV + (size_t)(b * SEQ + q0 + wv * 16 + l15) * 5120 + h * 128 + lg * 8;
#pragma unroll
      for (int c = 0; c < 4; ++c) {
        bf16x8 q = *(const bf16x8*)(qg + c * 32);
#pragma unroll
        for (int e = 0; e < 8; ++e) q[e] = (__bf16)((float)q[e] * QSCL);
        qf[c] = q;
      }
    }

    float m_st = -1e30f, l_st = 0.f;
    f32x4 accO[8] = {};

    for (int t = 0; t <= qb; ++t) {
      const int cur = t & 1;
      // ---- write V(t) regs -> Vt (transposed, swizzled). Implicit vmcnt
      // wait on vr covers the older K(t) gload_lds queue entries too. ----
      {
        union { uint4 u; ushort_t s[8]; } L0, L1, L2, L3;
        L0.u = vr0; L1.u = vr1; L2.u = vr2; L3.u = vr3;
#pragma unroll
        for (int dd = 0; dd < 8; ++dd) {
          int d = d8 + dd;
          uint2 w;
          w.x = (uint32)L0.s[dd] | ((uint32)L1.s[dd] << 16);
          w.y = (uint32)L2.s[dd] | ((uint32)L3.s[dd] << 16);
          int swz = ((d & 7) ^ ((d >> 3) & 3)) << 4;
          int off = (d * 128 + kv4 * 2) ^ swz;
          *(uint2*)((char*)Vt + off) = w;
        }
      }
      asm volatile("s_waitcnt lgkmcnt(0)" ::: "memory");
      __builtin_amdgcn_s_barrier();    // Kl[cur] + Vt ready; NO vmcnt drain

      // ---- prefetch tile t+1 (flies across the whole compute phase) ----
      if (t < qb) {
        const int kvn = (t + 1) * 64;
#pragma unroll
        for (int i = 0; i < 4; ++i) {
          int o = (i * 256 + tid) * 16;
          int row = o >> 8;
          int src = (o & 255) ^ ((row & 7) << 4);
          gload_lds16(QKV + kbase + (size_t)(kvn + row) * 5120 + (src >> 1),
                      (char*)&Kl[cur ^ 1][0] + o);
        }
        const ushort_t* vg = QKV + vbase + (size_t)(kvn + kv4) * 5120 + d8;
        vr0 = *(const uint4*)(vg);
        vr1 = *(const uint4*)(vg + 5120);
        vr2 = *(const uint4*)(vg + 10240);
        vr3 = *(const uint4*)(vg + 15360);
      }

      // ---- QK^T swapped: s[n] = S^T tile ----
      f32x4 s[4];
      __builtin_amdgcn_s_setprio(1);
#pragma unroll
      for (int n = 0; n < 4; ++n) {
        f32x4 z = {0.f, 0.f, 0.f, 0.f};
        s[n] = z;
#pragma unroll
        for (int c = 0; c < 4; ++c) {
          int row = n * 16 + l15;
          int boff = (row * 256 + c * 64 + lg * 16) ^ ((row & 7) << 4);
          bf16x8 kf = *(const bf16x8*)((const char*)Kl[cur] + boff);
          s[n] = MFMA16(kf, qf[c], s[n]);   // A=K, B=Q -> S^T
        }
      }
      __builtin_amdgcn_s_setprio(0);

      // causal mask (diag tile): kv = t*64 + 16n+4lg+r vs q = q0+wv*16+l15
      if (t == qb) {
        const int qg_ = wv * 16 + l15;    // q - q0
#pragma unroll
        for (int n = 0; n < 4; ++n)
#pragma unroll
          for (int r = 0; r < 4; ++r)
            if (n * 16 + lg * 4 + r > qg_) s[n][r] = -1e9f;
      }

      // ---- softmax (exp2 domain), kv-reduce = local + 2 shuffles ----
      float mx = fmaxf(fmaxf(fmaxf(s[0][0], s[0][1]), fmaxf(s[0][2], s[0][3])),
                       fmaxf(fmaxf(s[1][0], s[1][1]), fmaxf(s[1][2], s[1][3])));
      mx = fmaxf(mx, fmaxf(fmaxf(fmaxf(s[2][0], s[2][1]), fmaxf(s[2][2], s[2][3])),
                           fmaxf(fmaxf(s[3][0], s[3][1]), fmaxf(s[3][2], s[3][3]))));
      mx = fmaxf(mx, __shfl_xor(mx, 16, 64));
      mx = fmaxf(mx, __shfl_xor(mx, 32, 64));
      const float mnew = fmaxf(m_st, mx);
      const float alpha = __builtin_amdgcn_exp2f(m_st - mnew);
      m_st = mnew;

      float rsum = 0.f;
      uint32 dwA[4], dwB[4];
#pragma unroll
      for (int n = 0; n < 4; ++n) {
        float p0 = __builtin_amdgcn_exp2f(s[n][0] - mnew);
        float p1 = __builtin_amdgcn_exp2f(s[n][1] - mnew);
        float p2 = __builtin_amdgcn_exp2f(s[n][2] - mnew);
        float p3 = __builtin_amdgcn_exp2f(s[n][3] - mnew);
        rsum += (p0 + p1) + (p2 + p3);
        dwA[n] = (uint32)f2bf(p0) | ((uint32)f2bf(p1) << 16);
        dwB[n] = (uint32)f2bf(p2) | ((uint32)f2bf(p3) << 16);
      }
      rsum += __shfl_xor(rsum, 16, 64);
      rsum += __shfl_xor(rsum, 32, 64);
      l_st = l_st * alpha + rsum;
#pragma unroll
      for (int j = 0; j < 8; ++j)
#pragma unroll
        for (int r = 0; r < 4; ++r) accO[j][r] *= alpha;

      // ---- PV: accO[j] += mfma(Vt-frag, P^T-frag) per c-chunk ----
      const int s0l = (lane & 15) + 32 * (lg & 1);
#pragma unroll
      for (int c = 0; c < 2; ++c) {
        uint32 xA0 = __shfl((int)dwA[2 * c],     s0l,      64);
        uint32 xB0 = __shfl((int)dwB[2 * c],     s0l,      64);
        uint32 xA1 = __shfl((int)dwA[2 * c + 1], s0l,      64);
        uint32 xB1 = __shfl((int)dwB[2 * c + 1], s0l,      64);
        uint32 yA0 = __shfl((int)dwA[2 * c],     s0l + 16, 64);
        uint32 yB0 = __shfl((int)dwB[2 * c],     s0l + 16, 64);
        uint32 yA1 = __shfl((int)dwA[2 * c + 1], s0l + 16, 64);
        uint32 yB1 = __shfl((int)dwB[2 * c + 1], s0l + 16, 64);
        union { uint4 u; bf16x8 v; } pb;
        pb.u.x = a_sel ? xA1 : xA0;
        pb.u.y = a_sel ? xB1 : xB0;
        pb.u.z = a_sel ? yA1 : yA0;
        pb.u.w = a_sel ? yB1 : yB0;
        __builtin_amdgcn_s_setprio(1);
#pragma unroll
        for (int j = 0; j < 8; ++j) {
          int d = j * 16 + l15;
          int swz = ((d & 7) ^ ((d >> 3) & 3)) << 4;
          int off = (d * 128 + c * 64 + lg * 16) ^ swz;
          bf16x8 vf = *(const bf16x8*)((const char*)Vt + off);
          accO[j] = MFMA16(vf, pb.v, accO[j]);  // A=V^T, B=P^T -> O^T
        }
        __builtin_amdgcn_s_setprio(0);
      }
      __builtin_amdgcn_s_barrier();   // reads of Kl[cur]/Vt complete (reg deps)
    }

    // ---- epilogue: O^T lane layout: (d = 16j+4lg+r, q = l15) ----
    const float inv = 1.0f / l_st;
    ushort_t* og = O + (size_t)(b * SEQ + q0 + wv * 16 + l15) * 3072 + h * 128 + lg * 4;
#pragma unroll
    for (int j = 0; j < 8; ++j) {
      union { uint2 u; ushort_t s[4]; } w;
      w.s[0] = f2bf(accO[j][0] * inv);
      w.s[1] = f2bf(accO[j][1] * inv);
      w.s[2] = f2bf(accO[j][2] * inv);
      w.s[3] = f2bf(accO[j][3] * inv);
      *(uint2*)(og + j * 16) = w.u;
    }
  }
}

// ---------------------------------------------------------------------------
extern "C" void kernel_launch(void* const* d_in, const int* in_sizes, int n_in,
                              void* d_out, int out_size, void* d_ws, size_t ws_size,
                              hipStream_t stream) {
  const float* hs = (const float*)d_in[0];
  // d_in[1] = attention_mask (causal by construction; applied analytically)
  const float* Wq = (const float*)d_in[2];
  const float* bq = (const float*)d_in[3];
  const float* Wk = (const float*)d_in[4];
  const float* bk = (const float*)d_in[5];
  const float* Wv = (const float*)d_in[6];
  const float* bv = (const float*)d_in[7];
  const float* Wd = (const float*)d_in[8];
  const float* bd = (const float*)d_in[9];
  float* out = (float*)d_out;

  const size_t N_HS = (size_t)4096 * 3072;
  const size_t N_WQ = (size_t)3072 * 3072;
  const size_t N_WK = (size_t)1024 * 3072;

  ushort_t* hs_bf = (ushort_t*)d_ws;
  ushort_t* Wq_bf = hs_bf + N_HS;
  ushort_t* Wk_bf = Wq_bf + N_WQ;
  ushort_t* Wv_bf = Wk_bf + N_WK;
  ushort_t* Wd_bf = Wv_bf + N_WK;
  ushort_t* QKVw  = Wd_bf + N_WQ;            // [4096, 5120]
  ushort_t* Cw    = hs_bf;                   // ctx aliases hs_bf

  dim3 blk(256);
  cvt_kernel<<<2048, blk, 0, stream>>>(hs, hs_bf, (int)N_HS);
  cvt_kernel<<<2048, blk, 0, stream>>>(Wq, Wq_bf, (int)N_WQ);
  cvt_kernel<<<1024, blk, 0, stream>>>(Wk, Wk_bf, (int)N_WK);
  cvt_kernel<<<1024, blk, 0, stream>>>(Wv, Wv_bf, (int)N_WK);
  cvt_kernel<<<2048, blk, 0, stream>>>(Wd, Wd_bf, (int)N_WQ);

  qkv_gemm_kernel<<<dim3(1280), blk, 0, stream>>>(hs_bf, Wq_bf, Wk_bf, Wv_bf,
                                                  bq, bk, bv, QKVw);
  attn_kernel<<<dim3(48, 16), blk, 0, stream>>>(QKVw, Cw);
  gemm_bt_kernel<true><<<dim3(24 * 32), blk, 0, stream>>>(Cw, Wd_bf, bd, out, 3072, 3072, 24);
}